// Round 14
// baseline (67.323 us; speedup 1.0000x reference)
//
#include <hip/hip_runtime.h>

#define NN 2048
#define KK 32

typedef __attribute__((ext_vector_type(8))) short short8;   // 8 x bf16
typedef __attribute__((ext_vector_type(4))) float f32x4;

// workspace (bytes):
//  t_part: [512 blk][32b*32k*16z] f32   32 MiB @ 0
//  s_part: [512 blk][32b*32k*16z] f32   32 MiB @ 33554432
//  t     : [32 b][32 k][16 z] f32       64 KiB @ 67108864
#define WS_TPART 0UL
#define WS_SPART 33554432UL
#define WS_T     67108864UL
#define WS_NEED  67174400UL

__device__ __forceinline__ short8 pack8(const float* r) {
    short8 o;
#pragma unroll
    for (int e = 0; e < 8; ++e)
        o[e] = (short)(unsigned short)((__float_as_uint(r[e]) + 0x8000u) >> 16);
    return o;
}
__device__ __forceinline__ short8 sel8(bool keep, short8 v) {
    union { short8 s; unsigned u[4]; } a, b;
    a.s = v;
#pragma unroll
    for (int i = 0; i < 4; ++i) b.u[i] = keep ? a.u[i] : 0u;
    return b.s;
}

// ---------------- kT: t partials via MFMA (proven, no barriers) -------------
// grid 512 (4 j / block), block 512 = 8 waves; wave wv owns ck = wv*4..+4.
__global__ __launch_bounds__(512)
void kT(const float* __restrict__ x, const float* __restrict__ w,
        float* __restrict__ t_part)
{
    const int tid = threadIdx.x;
    const int wv = tid >> 6, l = tid & 63;
    const int z = l & 15, g = l >> 4;
    const int jl = g >> 1, ih = g & 1;
    const int j0 = blockIdx.x * 4;

    f32x4 C[4][2];
#pragma unroll
    for (int ckl = 0; ckl < 4; ++ckl)
#pragma unroll
        for (int bh = 0; bh < 2; ++bh) C[ckl][bh] = (f32x4){0.f, 0.f, 0.f, 0.f};

#pragma unroll
    for (int p = 0; p < 2; ++p) {
        const int jp = j0 + p * 2 + jl;
        short8 Af[2];
#pragma unroll
        for (int bh = 0; bh < 2; ++bh) {
            const float* xp = x + ((size_t)(bh * 16 + z) * NN + jp) * 16 + ih * 8;
            float ar[8];
            float4 v0 = *reinterpret_cast<const float4*>(xp);
            float4 v1 = *reinterpret_cast<const float4*>(xp + 4);
            ar[0]=v0.x; ar[1]=v0.y; ar[2]=v0.z; ar[3]=v0.w;
            ar[4]=v1.x; ar[5]=v1.y; ar[6]=v1.z; ar[7]=v1.w;
            Af[bh] = pack8(ar);
        }
        short8 Bf[4];
#pragma unroll
        for (int ckl = 0; ckl < 4; ++ckl) {
            const int ck = wv * 4 + ckl;
            const float* wp = w + ((size_t)ck * NN + jp) * 256 + ih * 128 + z;
            float br[8];
#pragma unroll
            for (int e = 0; e < 8; ++e) br[e] = wp[e * 16];
            Bf[ckl] = pack8(br);
        }
#pragma unroll
        for (int ckl = 0; ckl < 4; ++ckl)
#pragma unroll
            for (int bh = 0; bh < 2; ++bh)
                C[ckl][bh] = __builtin_amdgcn_mfma_f32_16x16x32_bf16(
                    Af[bh], Bf[ckl], C[ckl][bh], 0, 0, 0);
    }

    float* tp = t_part + (size_t)blockIdx.x * 16384;
#pragma unroll
    for (int ckl = 0; ckl < 4; ++ckl)
#pragma unroll
        for (int bh = 0; bh < 2; ++bh)
#pragma unroll
            for (int r = 0; r < 4; ++r)
                tp[((bh * 16 + g * 4 + r) * 32 + wv * 4 + ckl) * 16 + z] =
                    C[ckl][bh][r];
}

// ---------------- kredt: 512-row reduce -> t (one kernel) -------------------
// grid 256 (16 f32x4 cols each), block 1024 = 16 waves.
// Load: wave covers 16 cols x 4 row-subs -> 4 x 256B = 1KB per instruction.
__global__ __launch_bounds__(1024)
void kredt(const float* __restrict__ src, float* __restrict__ dst)
{
    __shared__ f32x4 red[64][17];
    const int tid = threadIdx.x;
    const int wv = tid >> 6, l = tid & 63;
    const int c = l & 15, rs = l >> 4;
    const int colg = blockIdx.x * 16 + c;
    const f32x4* P = reinterpret_cast<const f32x4*>(src);
    f32x4 a = (f32x4){0.f, 0.f, 0.f, 0.f};
#pragma unroll
    for (int q = 0; q < 8; ++q)
        a += P[(size_t)(wv * 32 + q * 4 + rs) * 4096 + colg];
    red[wv * 4 + rs][c] = a;
    __syncthreads();
    f32x4 s = (f32x4){0.f, 0.f, 0.f, 0.f};
    if (tid < 256) {
        const int cc = tid & 15, r0 = tid >> 4;
        s = (red[r0 * 4 + 0][cc] + red[r0 * 4 + 1][cc])
          + (red[r0 * 4 + 2][cc] + red[r0 * 4 + 3][cc]);
    }
    __syncthreads();
    if (tid < 256) red[tid >> 4][tid & 15] = s;
    __syncthreads();
    if (tid < 16) {
        f32x4 o = (f32x4){0.f, 0.f, 0.f, 0.f};
#pragma unroll
        for (int r = 0; r < 16; ++r) o += red[r][tid];
        reinterpret_cast<f32x4*>(dst)[blockIdx.x * 16 + tid] = o;
    }
}

// ---------------- kBF: fused recompute-u + logits + softmax + s -------------
// grid 512 (4 j / block -> 2 blocks/CU, barriers overlap), block 512 = 8 waves.
// u recompute: A = w (M=z), B = x (N=b) masked per j; u lives in C regs.
__global__ __launch_bounds__(512)
void kBF(const float* __restrict__ x, const float* __restrict__ w,
         const float* __restrict__ t, const float* __restrict__ bias,
         float* __restrict__ s_part)
{
    __shared__ float t_lds[32 * 520];   // [b][520] pad (66.6 KB)
    __shared__ float l_lds[32][33];
    __shared__ float c_lds[32][33];
    __shared__ float b_lds[32][4];
    const int tid = threadIdx.x;
    const int wv = tid >> 6, l = tid & 63;
    const int c16 = l & 15, g = l >> 4;
    const int jl = g >> 1, ih = g & 1;
    const int j0 = blockIdx.x * 4;

    {
        const f32x4* tg = reinterpret_cast<const f32x4*>(t);
#pragma unroll
        for (int q = 0; q < 8; ++q) {
            const int idx4 = q * 512 + tid;
            const int b = idx4 >> 7, col4 = idx4 & 127;
            *reinterpret_cast<f32x4*>(&t_lds[b * 520 + col4 * 4]) = tg[idx4];
        }
        if (tid < 128)
            b_lds[tid >> 2][tid & 3] = bias[(size_t)(tid >> 2) * NN + j0 + (tid & 3)];
    }
    __syncthreads();

    f32x4 S[4][2];
#pragma unroll
    for (int ckl = 0; ckl < 4; ++ckl)
#pragma unroll
        for (int bn = 0; bn < 2; ++bn) S[ckl][bn] = (f32x4){0.f, 0.f, 0.f, 0.f};

#pragma unroll 1
    for (int p = 0; p < 2; ++p) {
        const int jp = j0 + p * 2 + jl;

        short8 Wf[4];
#pragma unroll
        for (int ckl = 0; ckl < 4; ++ckl) {
            const int k = wv * 4 + ckl;
            const float* wp = w + ((size_t)k * NN + jp) * 256 + ih * 128 + c16;
            float br[8];
#pragma unroll
            for (int e = 0; e < 8; ++e) br[e] = wp[e * 16];
            Wf[ckl] = pack8(br);
        }
        short8 Xf[2];
#pragma unroll
        for (int bn = 0; bn < 2; ++bn) {
            const float* xp = x + ((size_t)(bn * 16 + c16) * NN + jp) * 16 + ih * 8;
            float ar[8];
            float4 v0 = *reinterpret_cast<const float4*>(xp);
            float4 v1 = *reinterpret_cast<const float4*>(xp + 4);
            ar[0]=v0.x; ar[1]=v0.y; ar[2]=v0.z; ar[3]=v0.w;
            ar[4]=v1.x; ar[5]=v1.y; ar[6]=v1.z; ar[7]=v1.w;
            Xf[bn] = pack8(ar);
        }

#pragma unroll 1
        for (int jj = 0; jj < 2; ++jj) {
            const bool keep = (jl == jj);
            const f32x4 zero = (f32x4){0.f, 0.f, 0.f, 0.f};

            f32x4 C[4][2];
#pragma unroll
            for (int ckl = 0; ckl < 4; ++ckl) {
                const short8 wsel = sel8(keep, Wf[ckl]);
                const int k = wv * 4 + ckl;
#pragma unroll
                for (int bn = 0; bn < 2; ++bn) {
                    C[ckl][bn] = __builtin_amdgcn_mfma_f32_16x16x32_bf16(
                        wsel, Xf[bn], zero, 0, 0, 0);
                    const int b = bn * 16 + c16;
                    const f32x4 tv = *reinterpret_cast<const f32x4*>(
                        &t_lds[b * 520 + k * 16 + g * 4]);
                    float pv = C[ckl][bn][0] * tv[0] + C[ckl][bn][1] * tv[1]
                             + C[ckl][bn][2] * tv[2] + C[ckl][bn][3] * tv[3];
                    pv += __shfl_xor(pv, 16);
                    pv += __shfl_xor(pv, 32);
                    if (g == 0) l_lds[b][k] = pv;
                }
            }
            __syncthreads();

            {
                const int bb = tid >> 4, kq = tid & 15;
                const float lv0 = l_lds[bb][2 * kq];
                const float lv1 = l_lds[bb][2 * kq + 1];
                float m = fmaxf(lv0, lv1);
                m = fmaxf(m, __shfl_xor(m, 1));
                m = fmaxf(m, __shfl_xor(m, 2));
                m = fmaxf(m, __shfl_xor(m, 4));
                m = fmaxf(m, __shfl_xor(m, 8));
                const float e0 = __expf((lv0 - m) * 0.25f);
                const float e1 = __expf((lv1 - m) * 0.25f);
                float sum = e0 + e1;
                sum += __shfl_xor(sum, 1);
                sum += __shfl_xor(sum, 2);
                sum += __shfl_xor(sum, 4);
                sum += __shfl_xor(sum, 8);
                const float inv = 1.f / sum;
                const int jloc = p * 2 + jj;
                c_lds[bb][2 * kq]     = e0 * inv + b_lds[2 * kq][jloc];
                c_lds[bb][2 * kq + 1] = e1 * inv + b_lds[2 * kq + 1][jloc];
            }
            __syncthreads();

#pragma unroll
            for (int ckl = 0; ckl < 4; ++ckl) {
                const int k = wv * 4 + ckl;
#pragma unroll
                for (int bn = 0; bn < 2; ++bn) {
                    const float cv = c_lds[bn * 16 + c16][k];
#pragma unroll
                    for (int r = 0; r < 4; ++r)
                        S[ckl][bn][r] = fmaf(cv, C[ckl][bn][r], S[ckl][bn][r]);
                }
            }
        }
    }

    float* sp = s_part + (size_t)blockIdx.x * 16384;
#pragma unroll
    for (int ckl = 0; ckl < 4; ++ckl) {
        const int k = wv * 4 + ckl;
#pragma unroll
        for (int bn = 0; bn < 2; ++bn)
            *reinterpret_cast<f32x4*>(
                &sp[(bn * 16 + c16) * 512 + k * 16 + g * 4]) = S[ckl][bn];
    }
}

// ---------------- kredsq: 512-row reduce + squash (one kernel) --------------
// grid 256, block 1024; same load shape as kredt, squash tail.
__global__ __launch_bounds__(1024)
void kredsq(const float* __restrict__ src, float* __restrict__ out)
{
    __shared__ f32x4 red[64][17];
    const int tid = threadIdx.x;
    const int wv = tid >> 6, l = tid & 63;
    const int c = l & 15, rs = l >> 4;
    const int colg = blockIdx.x * 16 + c;
    const f32x4* P = reinterpret_cast<const f32x4*>(src);
    f32x4 a = (f32x4){0.f, 0.f, 0.f, 0.f};
#pragma unroll
    for (int q = 0; q < 8; ++q)
        a += P[(size_t)(wv * 32 + q * 4 + rs) * 4096 + colg];
    red[wv * 4 + rs][c] = a;
    __syncthreads();
    f32x4 s = (f32x4){0.f, 0.f, 0.f, 0.f};
    if (tid < 256) {
        const int cc = tid & 15, r0 = tid >> 4;
        s = (red[r0 * 4 + 0][cc] + red[r0 * 4 + 1][cc])
          + (red[r0 * 4 + 2][cc] + red[r0 * 4 + 3][cc]);
    }
    __syncthreads();
    if (tid < 256) red[tid >> 4][tid & 15] = s;
    __syncthreads();
    if (tid < 16) {
        f32x4 o = (f32x4){0.f, 0.f, 0.f, 0.f};
#pragma unroll
        for (int r = 0; r < 16; ++r) o += red[r][tid];
        // colg groups of 4 consecutive = one (b,k); lanes 0..15, zq = tid&3
        float ss = o.x * o.x + o.y * o.y + o.z * o.z + o.w * o.w;
        ss += __shfl_xor(ss, 1);
        ss += __shfl_xor(ss, 2);
        const float n = sqrtf(ss);
        const float sc = (1.f - 1.f / (__expf(n) + 1e-20f)) / (n + 1e-20f);
        f32x4 r; r.x = o.x * sc; r.y = o.y * sc; r.z = o.z * sc; r.w = o.w * sc;
        reinterpret_cast<f32x4*>(out)[blockIdx.x * 16 + tid] = r;
    }
}

// sentinel if workspace too small
__global__ void k_sentinel(float* __restrict__ out)
{
    out[blockIdx.x * 256 + threadIdx.x] = 12345.0f;
}

extern "C" void kernel_launch(void* const* d_in, const int* in_sizes, int n_in,
                              void* d_out, int out_size, void* d_ws, size_t ws_size,
                              hipStream_t stream)
{
    const float* x    = (const float*)d_in[0];
    const float* w    = (const float*)d_in[1];
    const float* bias = (const float*)d_in[2];
    float* out        = (float*)d_out;

    char* ws = (char*)d_ws;
    if (ws_size < WS_NEED) {
        k_sentinel<<<dim3(64), dim3(256), 0, stream>>>(out);
        return;
    }
    float* t_part = (float*)(ws + WS_TPART);
    float* s_part = (float*)(ws + WS_SPART);
    float* t      = (float*)(ws + WS_T);

    kT    <<<dim3(512), dim3(512),  0, stream>>>(x, w, t_part);
    kredt <<<dim3(256), dim3(1024), 0, stream>>>(t_part, t);
    kBF   <<<dim3(512), dim3(512),  0, stream>>>(x, w, t, bias, s_part);
    kredsq<<<dim3(256), dim3(1024), 0, stream>>>(s_part, out);
}